// Round 9
// baseline (220.602 us; speedup 1.0000x reference)
//
#include <hip/hip_runtime.h>
#include <hip/hip_bf16.h>

#define NB 2048
#define NNODES 64
#define HD 128
#define NEDGE 512
#define OSTRIDE 2017

using bf16x8 = __attribute__((ext_vector_type(8))) __bf16;
using f32x4  = __attribute__((ext_vector_type(4))) float;
using u32x4  = __attribute__((ext_vector_type(4))) unsigned int;

typedef __attribute__((address_space(1))) void gvoid;
typedef __attribute__((address_space(3))) void lvoid;

// XOR swizzle for [64][128] bf16 tiles (256-B rows).
__device__ __forceinline__ int swz(int row, int cb){ return (row<<8) + (cb ^ ((row&7)<<4)); }

__device__ __forceinline__ unsigned short bf16r(float x){
  unsigned u = __float_as_uint(x);
  return (unsigned short)((u + 0x7fffu + ((u>>16)&1u)) >> 16);  // RNE
}
__device__ __forceinline__ unsigned pack2(float a, float b){
  unsigned ua = __float_as_uint(a); ua = (ua + 0x7fffu + ((ua>>16)&1u)) >> 16;
  unsigned ub = __float_as_uint(b); ub = (ub + 0x7fffu + ((ub>>16)&1u)) & 0xffff0000u;
  return ua | ub;
}
__device__ __forceinline__ void unpack8(u32x4 u, float* f){
#pragma unroll
  for (int i=0;i<4;++i){
    unsigned w = u[i];
    f[2*i]   = __uint_as_float(w << 16);
    f[2*i+1] = __uint_as_float(w & 0xffff0000u);
  }
}
__device__ __forceinline__ bf16x8 asbf8(u32x4 u){ return __builtin_bit_cast(bf16x8, u); }
#define MFMA __builtin_amdgcn_mfma_f32_16x16x32_bf16

// ---- prep: bf16 [n][k-swz] slabs; Wc = W2@pW1 merged; plus eW1^T and triu table.
// ws (bf16 elems): w1 @0 (3x16384), wc @49152, pw2 @98304, emb @147456 (8192),
// bc f32[3][128] @155648 (768 slots), eW1T @156416 (16384), triuTab u32[2016] @172800
// (4032 slots). Total 176832 elems = 353664 B.
__global__ void prep_wts(const float* __restrict__ g1, const float* __restrict__ g2,
                         const float* __restrict__ p1, const float* __restrict__ p2,
                         const float* __restrict__ b2, const float* __restrict__ pb1,
                         const float* __restrict__ emb, const float* __restrict__ eW1,
                         unsigned short* __restrict__ ws)
{
  int idx = blockIdx.x*256 + threadIdx.x;
  if (idx < 49152){            // W1^T swizzled
    int l = idx/16384, r = idx%16384, n = r>>7, m = r&127;
    int k = (((m>>3) ^ (n&7))<<3) | (m&7);
    ws[idx] = bf16r(g1[l*16384 + k*128 + n]);
  } else if (idx < 98304){     // Wc^T swizzled, Wc = W2 @ pW1 (f32 accumulate)
    int q = idx - 49152;
    int l = q/16384, r = q%16384, n = r>>7, m = r&127;
    int k = (((m>>3) ^ (n&7))<<3) | (m&7);
    const float* W2 = g2 + l*16384;
    const float* P1 = p1 + l*16384;
    float s = 0.f;
    for (int mm=0; mm<128; ++mm) s = fmaf(W2[k*128+mm], P1[mm*128+n], s);
    ws[idx] = bf16r(s);
  } else if (idx < 147456){    // pW2^T swizzled
    int q = idx - 98304;
    int l = q/16384, r = q%16384, n = r>>7, m = r&127;
    int k = (((m>>3) ^ (n&7))<<3) | (m&7);
    ws[idx] = bf16r(p2[l*16384 + k*128 + n]);
  } else if (idx < 155648){    // emb bf16
    ws[idx] = bf16r(emb[idx - 147456]);
  } else if (idx < 156032){    // bc[l][n] = b2[l]@pW1[l][:,n] + pb1[l][n]  (f32)
    int q = idx - 155648, l = q/128, n = q%128;
    const float* P1 = p1 + l*16384;
    const float* B2 = b2 + l*128;
    float s = pb1[l*128 + n];
    for (int mm=0; mm<128; ++mm) s = fmaf(B2[mm], P1[mm*128+n], s);
    ((float*)(ws + 155648))[q] = s;
  } else if (idx >= 156416 && idx < 172800){   // eW1^T bf16 [n][k]
    int q = idx - 156416, n = q>>7, k = q&127;
    ws[idx] = bf16r(eW1[k*128 + n]);
  } else if (idx >= 172800 && idx < 174816){   // triu (i,j) table
    int p = idx - 172800;
    float fi = (127.0f - sqrtf((float)(16129 - 8*p))) * 0.5f;
    int i = (int)fi;
    if (i > 62) i = 62;
    if (i < 0)  i = 0;
    while ((i+1)*(127-(i+1))/2 <= p) ++i;
    while (i*(127-i)/2 > p) --i;
    int j = i + 1 + (p - i*(127-i)/2);
    ((unsigned*)(ws + 172800))[p] = ((unsigned)i << 16) | (unsigned)j;
  }
}

// Async-stage one 16 KB half-slab (64 rows x 256 B) global->LDS, linear copy.
__device__ __forceinline__ void stage(const unsigned short* g, unsigned char* lbuf, int t){
  const int l = t & 63, w = t >> 6;
  const unsigned char* gb = (const unsigned char*)g;
#pragma unroll
  for (int i=0;i<4;++i){
    int base = ((i*4 + w) << 10);
    __builtin_amdgcn_global_load_lds((gvoid*)(gb + base + l*16), (lvoid*)(lbuf + base), 16, 0, 0);
  }
}

// Load this wave's 8 B-frags (col-halves c and c+64) from the staged LDS buffers.
__device__ __forceinline__ void ldw(const unsigned char* bufA, const unsigned char* bufB,
                                    int t, u32x4* wf){
  const int l = t & 63, w = t >> 6, lr = l & 15, lk = l >> 4;
  int rb = (w*16 + lr) << 8, sw = ((w*16 + lr) & 7) << 4;
#pragma unroll
  for (int ks=0; ks<4; ++ks){
    int off = rb + ((ks*64 + lk*16) ^ sw);
    wf[ks]   = *(const u32x4*)(bufA + off);
    wf[4+ks] = *(const u32x4*)(bufB + off);
  }
}

// y = x @ W from reg-held B-frags, writing y TRANSPOSED (yT [feat][node]) into LDS.
__device__ __forceinline__ void gemm_yT(const unsigned char* xs, const u32x4* wf,
                                        unsigned char* yT, int t)
{
  const int l = t & 63, w = t >> 6, lr = l & 15, lk = l >> 4;
  f32x4 acc[4][2] = {};
#pragma unroll
  for (int ks=0; ks<4; ++ks){
    int kByte = ks*64 + lk*16;
#pragma unroll
    for (int rt=0; rt<4; ++rt){
      bf16x8 af = asbf8(*(const u32x4*)(xs + swz(rt*16 + lr, kByte)));
      acc[rt][0] = MFMA(af, asbf8(wf[ks]),   acc[rt][0], 0,0,0);
      acc[rt][1] = MFMA(af, asbf8(wf[4+ks]), acc[rt][1], 0,0,0);
    }
  }
#pragma unroll
  for (int rt=0; rt<4; ++rt){
#pragma unroll
    for (int h=0; h<2; ++h){
      int n = h*64 + w*16 + lr;                 // output col = yT row
      unsigned w0 = pack2(acc[rt][h][0], acc[rt][h][1]);
      unsigned w1 = pack2(acc[rt][h][2], acc[rt][h][3]);
      int cb = (rt*32 + lk*8) ^ ((n&7)<<4);
      *(unsigned long long*)(yT + (n<<7) + cb) = ((unsigned long long)w1 << 32) | w0;
    }
  }
}

// In-place 64x128 = (64x128)@(128x128) + bias from reg-held B-frags, optional relu.
template<int RELU>
__device__ __forceinline__ void gemm_st(unsigned char* hb, const u32x4* wf,
                                        const float* __restrict__ bias, int t)
{
  const int l = t & 63, w = t >> 6, lr = l & 15, lk = l >> 4;
  f32x4 acc[4][2] = {};
#pragma unroll
  for (int ks=0; ks<4; ++ks){
    int kByte = ks*64 + lk*16;
#pragma unroll
    for (int rt=0; rt<4; ++rt){
      bf16x8 af = asbf8(*(const u32x4*)(hb + swz(rt*16 + lr, kByte)));
      acc[rt][0] = MFMA(af, asbf8(wf[ks]),   acc[rt][0], 0,0,0);
      acc[rt][1] = MFMA(af, asbf8(wf[4+ks]), acc[rt][1], 0,0,0);
    }
  }
  int c0 = w*16 + lr, c1 = 64 + w*16 + lr;
  float b0 = bias[c0], b1 = bias[c1];
  __syncthreads();   // all A-reads complete; also drains this phase's staging
  int cb0 = c0*2, cb1 = c1*2;
#pragma unroll
  for (int rt=0; rt<4; ++rt){
#pragma unroll
    for (int r=0; r<4; ++r){
      int row = rt*16 + lk*4 + r;
      float v0 = acc[rt][0][r] + b0;
      float v1 = acc[rt][1][r] + b1;
      if (RELU){ v0 = fmaxf(v0, 0.f); v1 = fmaxf(v1, 0.f); }
      *(unsigned short*)(hb + swz(row, cb0)) = bf16r(v0);
      *(unsigned short*)(hb + swz(row, cb1)) = bf16r(v1);
    }
  }
}

// h = A' @ y + bias   (A' [64][64] bf16 swizzled in sA; y as yT rows in sH). In-place on sH.
__device__ __forceinline__ void gemm_aggA(const unsigned char* sA, unsigned char* sH,
                                          const float* __restrict__ bias, int t)
{
  const int l = t & 63, w = t >> 6, lr = l & 15, lk = l >> 4;
  f32x4 acc[4][2] = {};
#pragma unroll
  for (int ks=0; ks<2; ++ks){
    int kB = ks*64 + lk*16;
    bf16x8 bfr[2];
#pragma unroll
    for (int ft=0; ft<2; ++ft){
      int n = w*32 + ft*16 + lr;                // feat = yT row
      bfr[ft] = asbf8(*(const u32x4*)(sH + (n<<7) + (kB ^ ((n&7)<<4))));
    }
#pragma unroll
    for (int rt=0; rt<4; ++rt){
      int m = rt*16 + lr;
      bf16x8 af = asbf8(*(const u32x4*)(sA + (m<<7) + (kB ^ ((m&7)<<4))));
      acc[rt][0] = MFMA(af, bfr[0], acc[rt][0], 0,0,0);
      acc[rt][1] = MFMA(af, bfr[1], acc[rt][1], 0,0,0);
    }
  }
  float b0 = bias[w*32 + lr], b1 = bias[w*32 + 16 + lr];
  __syncthreads();   // all yT reads complete before overwrite
  int cb0 = (w*32 + lr)*2, cb1 = (w*32 + 16 + lr)*2;
#pragma unroll
  for (int rt=0; rt<4; ++rt){
#pragma unroll
    for (int r=0; r<4; ++r){
      int row = rt*16 + lk*4 + r;
      *(unsigned short*)(sH + swz(row, cb0)) = bf16r(acc[rt][0][r] + b0);
      *(unsigned short*)(sH + swz(row, cb1)) = bf16r(acc[rt][1][r] + b1);
    }
  }
}

// LayerNorm over rows of a [64][128] bf16 tile. thread t: row t>>2, quarter t&3.
template<int RELU, int RESID>
__device__ __forceinline__ void ln_rows(const unsigned char* inb, const unsigned char* resb,
                                        const float* __restrict__ g, const float* __restrict__ bb,
                                        unsigned char* outb, int t)
{
  int r = t >> 2, q = t & 3;
  int cb0 = q*64, c0 = q*32;
  float v[32];
#pragma unroll
  for (int i=0;i<4;++i){ u32x4 u = *(const u32x4*)(inb + swz(r, cb0 + i*16)); unpack8(u, v + i*8); }
  if constexpr (RESID){
#pragma unroll
    for (int i=0;i<4;++i){
      u32x4 u = *(const u32x4*)(resb + swz(r, cb0 + i*16));
      float x[8]; unpack8(u, x);
#pragma unroll
      for (int j=0;j<8;++j) v[i*8+j] += x[j];
    }
  }
  float s=0.f, s2=0.f;
#pragma unroll
  for (int i=0;i<32;++i){ s += v[i]; s2 += v[i]*v[i]; }
  s += __shfl_xor(s, 1); s2 += __shfl_xor(s2, 1);
  s += __shfl_xor(s, 2); s2 += __shfl_xor(s2, 2);
  float mu  = s * (1.f/128.f);
  float var = s2 * (1.f/128.f) - mu*mu;
  float rs  = rsqrtf(var + 1e-5f);
#pragma unroll
  for (int i=0;i<8;++i){
    f32x4 gv = *(const f32x4*)(g + c0 + i*4);
    f32x4 bv = *(const f32x4*)(bb + c0 + i*4);
#pragma unroll
    for (int j=0;j<4;++j){
      float val = (v[i*4+j]-mu)*rs*gv[j] + bv[j];
      if (RELU) val = fmaxf(val, 0.f);
      v[i*4+j] = val;
    }
  }
#pragma unroll
  for (int i=0;i<4;++i){
    u32x4 u;
#pragma unroll
    for (int j=0;j<4;++j) u[j] = pack2(v[i*8+2*j], v[i*8+2*j+1]);
    *(u32x4*)(outb + swz(r, cb0 + i*16)) = u;
  }
}

__global__ __launch_bounds__(256, 2) void gnn_fused(
    const int* __restrict__ nf, const int* __restrict__ ei,
    const unsigned short* __restrict__ wsb,
    const float* __restrict__ gb1, const float* __restrict__ glng, const float* __restrict__ glnb,
    const float* __restrict__ pb2,
    const float* __restrict__ nmg, const float* __restrict__ nmb,
    const float* __restrict__ eb1,
    const float* __restrict__ elng, const float* __restrict__ elnb,
    const float* __restrict__ eW2, const float* __restrict__ eb2,
    float* __restrict__ out)
{
  __shared__ __align__(16) unsigned char sX[16384];   // x tile [64][128] bf16 swizzled
  __shared__ __align__(16) unsigned char sH[16384];   // counts / yT / h / dots f32[64][64]
  __shared__ __align__(16) unsigned char sA[8192];    // feats -> A' -> exit scratch
  __shared__ __align__(16) unsigned char wbA[16384];  // weight half-slab transit
  __shared__ __align__(16) unsigned char wbB[16384];

  const int b = blockIdx.x, t = threadIdx.x;
  const int l = t & 63, w = t >> 6, lr = l & 15, lk = l >> 4;

  const unsigned short* wg1 = wsb;
  const unsigned short* wwc = wsb + 49152;
  const unsigned short* wp2 = wsb + 98304;
  const unsigned short* wem = wsb + 147456;
  const float*          bcf = (const float*)(wsb + 155648);
  const unsigned short* eT  = wsb + 156416;
  const unsigned*       tab = (const unsigned*)(wsb + 172800);

  // ---- setup: feats into sA, zero counts in sH ----
  if (t < NNODES) ((int*)sA)[t] = nf[b*NNODES + t];
  {
    u32x4 z = {0,0,0,0};
#pragma unroll
    for (int i=0;i<4;++i) *(u32x4*)(sH + t*64 + i*16) = z;   // 4096 ints zeroed
  }
  __syncthreads();

  // x0 = emb[feat] ; edge multiplicity counts via LDS atomics
  {
    int n = t >> 2, q = t & 3;
    int f = ((const int*)sA)[n];
    const unsigned char* er = (const unsigned char*)(wem + f*HD) + q*64;
#pragma unroll
    for (int i=0;i<4;++i){
      u32x4 u = *(const u32x4*)(er + i*16);
      *(u32x4*)(sX + swz(n, q*64 + i*16)) = u;
    }
  }
  {
    int* cnts = (int*)sH;
#pragma unroll
    for (int e = t; e < NEDGE; e += 256){
      int sg = (ei[b*NEDGE + e]            - b*NNODES) & 63;
      int dg = (ei[NB*NEDGE + b*NEDGE + e] - b*NNODES) & 63;
      atomicAdd(&cnts[dg*64 + sg], 1);
    }
  }
  __syncthreads();

  // stage layer-0 W1 (overlaps A'-build) + A' = A+I bf16 [64][64] swizzled into sA
  stage(wg1,        wbA, t);
  stage(wg1 + 8192, wbB, t);
  {
    const int* cnts = (const int*)sH;
    int n = t >> 2, c0 = (t & 3) * 16;
    unsigned short o[16];
#pragma unroll
    for (int j=0;j<16;++j){
      int v = cnts[n*64 + c0 + j];
      if (c0 + j == n) v += 1;
      o[j] = bf16r((float)v);
    }
    u32x4 u0, u1;
#pragma unroll
    for (int j=0;j<4;++j){
      u0[j] = (unsigned)o[2*j]   | ((unsigned)o[2*j+1] << 16);
      u1[j] = (unsigned)o[8+2*j] | ((unsigned)o[9+2*j] << 16);
    }
    *(u32x4*)(sA + (n<<7) + ((c0*2)      ^ ((n&7)<<4))) = u0;
    *(u32x4*)(sA + (n<<7) + ((c0*2 + 16) ^ ((n&7)<<4))) = u1;
  }
  __syncthreads();   // drains wg1 staging

  u32x4 wf[8];
  ldw(wbA, wbB, t, wf);       // W1[0] -> regs
  __syncthreads();            // transit free

  for (int i=0; i<3; ++i){
    // P1: stage Wc; yT = (x@W1)^T -> sH
    stage(wwc + i*16384,        wbA, t);
    stage(wwc + i*16384 + 8192, wbB, t);
    gemm_yT(sX, wf, sH, t);
    __syncthreads();                                   // yT visible; Wc staged
    // P2: h = A'@y + b1 (in-place sH, internal bar); pull Wc frags
    gemm_aggA(sA, sH, gb1 + i*HD, t);
    ldw(wbA, wbB, t, wf);
    __syncthreads();                                   // transit free
    // P3: stage pW2; u = relu(LN(h)) in-place
    stage(wp2 + i*16384,        wbA, t);
    stage(wp2 + i*16384 + 8192, wbB, t);
    ln_rows<1,0>(sH, nullptr, glng + i*HD, glnb + i*HD, sH, t);
    __syncthreads();                                   // pW2 staged (drain)
    // P4: v = relu(u@Wc + bc) in-place (internal bar); pull pW2 frags
    gemm_st<1>(sH, wf, bcf + i*HD, t);
    ldw(wbA, wbB, t, wf);
    __syncthreads();                                   // transit free
    // P5: stage next W1; h = v@pW2 + pb2 in-place (internal bar drains); pull W1
    if (i < 2){
      stage(wg1 + (i+1)*16384,        wbA, t);
      stage(wg1 + (i+1)*16384 + 8192, wbB, t);
    }
    gemm_st<0>(sH, wf, pb2 + i*HD, t);
    if (i < 2) ldw(wbA, wbB, t, wf);
    __syncthreads();
    // P6: x = LN(h [+x]) -> sX
    if (i == 0) ln_rows<0,0>(sH, nullptr, nmg, nmb, sX, t);
    else        ln_rows<0,1>(sH, sX,      nmg, nmb, sX, t);
    __syncthreads();
  }

  // exit-head scratch layout in sA (A' dead after layer 2's aggA... but sA read in
  // every layer's aggA; now fully dead): part[256] @0, meansv[128] @256,
  // m1p[256] @384, m1[128] @640  (f32 indices)
  float* part   = (float*)sA;
  float* meansv = (float*)sA + 256;
  float* m1p    = (float*)sA + 384;
  float* m1     = (float*)sA + 640;

  // ---- T1: dots MFMA (sX -> sH dotsf)  ||  column part-sums (sX -> sA part) ----
  {
    f32x4 dacc[4] = {};
#pragma unroll
    for (int ks=0; ks<4; ++ks){
      int kByte = ks*64 + lk*16;
      bf16x8 af = asbf8(*(const u32x4*)(sX + swz(w*16 + lr, kByte)));
#pragma unroll
      for (int ct=0; ct<4; ++ct){
        bf16x8 bf = asbf8(*(const u32x4*)(sX + swz(ct*16 + lr, kByte)));
        dacc[ct] = MFMA(af, bf, dacc[ct], 0,0,0);
      }
    }
    float* dotsf = (float*)sH;
#pragma unroll
    for (int ct=0; ct<4; ++ct){
#pragma unroll
      for (int r=0; r<4; ++r){
        int row = w*16 + lk*4 + r;
        int col = (ct*16 + lr) ^ (((row>>2)&1)<<4);
        dotsf[row*64 + col] = dacc[ct][r] * 0.08838834764831843f;
      }
    }
  }
  {
    int c = t & 127, half = t >> 7;
    float s = 0.f;
#pragma unroll
    for (int r2=0; r2<32; ++r2){
      int r = half*32 + r2;
      unsigned short u = *(const unsigned short*)(sX + swz(r, 2*c));
      s += __uint_as_float(((unsigned)u) << 16);
    }
    part[half*128 + c] = s;
  }
  __syncthreads();

  // ---- T2: meansv (tiny) + triu table-extraction ----
  if (t < 128) meansv[t] = (part[t] + part[128 + t]) * (1.f/64.f);
  {
    const float* dotsf = (const float*)sH;
#pragma unroll
    for (int p = t; p < 2016; p += 256){
      unsigned ij = tab[p];
      int i = (int)(ij >> 16), j = (int)(ij & 0xffffu);
      int jc = j ^ (((i>>2)&1)<<4);
      out[(size_t)b*OSTRIDE + p] = dotsf[i*64 + jc];
    }
  }
  __syncthreads();

  // ---- T3: m1 = means @ eW1 + eb1, 2 lanes per output col (k-split halves) ----
  {
    int c = t & 127, half = t >> 7;
    const unsigned short* er = eT + c*128 + half*64;
    float s = 0.f;
#pragma unroll
    for (int kk=0; kk<8; ++kk){
      u32x4 u = *(const u32x4*)(er + kk*8);
      float f[8]; unpack8(u, f);
#pragma unroll
      for (int j=0;j<8;++j) s += meansv[half*64 + kk*8 + j] * f[j];
    }
    m1p[half*128 + c] = s;
  }
  __syncthreads();
  if (t < 128) m1[t] = m1p[t] + m1p[128 + t] + eb1[t];
  __syncthreads();

  // ---- T4: exit LN + final dot (wave 0) ----
  if (t < 64){
    float v0 = m1[t], v1 = m1[t+64];
    float s = v0 + v1, s2 = v0*v0 + v1*v1;
#pragma unroll
    for (int d=1; d<64; d<<=1){ s += __shfl_xor(s, d); s2 += __shfl_xor(s2, d); }
    float mu  = s * (1.f/128.f);
    float var = s2 * (1.f/128.f) - mu*mu;
    float rs  = rsqrtf(var + 1e-5f);
    float e0 = fmaxf((v0-mu)*rs*elng[t]    + elnb[t],    0.f);
    float e1 = fmaxf((v1-mu)*rs*elng[t+64] + elnb[t+64], 0.f);
    float pd = e0*eW2[t] + e1*eW2[t+64];
#pragma unroll
    for (int d=1; d<64; d<<=1) pd += __shfl_xor(pd, d);
    if (t == 0) out[(size_t)b*OSTRIDE + 2016] = pd + eb2[0];
  }
}

extern "C" void kernel_launch(void* const* d_in, const int* in_sizes, int n_in,
                              void* d_out, int out_size, void* d_ws, size_t ws_size,
                              hipStream_t stream)
{
  const int*   nf   = (const int*)d_in[0];
  const int*   ei   = (const int*)d_in[1];
  // d_in[2] = ptr (uniform 64-node graphs, unused)
  const float* emb  = (const float*)d_in[3];
  const float* gW1  = (const float*)d_in[4];
  const float* gb1  = (const float*)d_in[5];
  const float* glng = (const float*)d_in[6];
  const float* glnb = (const float*)d_in[7];
  const float* gW2  = (const float*)d_in[8];
  const float* gb2  = (const float*)d_in[9];
  const float* pW1  = (const float*)d_in[10];
  const float* pb1  = (const float*)d_in[11];
  const float* pW2  = (const float*)d_in[12];
  const float* pb2  = (const float*)d_in[13];
  const float* nmg  = (const float*)d_in[14];
  const float* nmb  = (const float*)d_in[15];
  const float* eW1  = (const float*)d_in[16];
  const float* eb1  = (const float*)d_in[17];
  const float* elng = (const float*)d_in[18];
  const float* elnb = (const float*)d_in[19];
  const float* eW2  = (const float*)d_in[20];
  const float* eb2  = (const float*)d_in[21];
  (void)in_sizes; (void)n_in; (void)out_size;

  if (ws_size < 176832u * sizeof(unsigned short)) return;
  unsigned short* wsb = (unsigned short*)d_ws;

  prep_wts<<<683, 256, 0, stream>>>(gW1, gW2, pW1, pW2, gb2, pb1, emb, eW1, wsb);
  gnn_fused<<<NB, 256, 0, stream>>>(nf, ei, wsb, gb1, glng, glnb, pb2,
                                    nmg, nmb, eb1, elng, elnb, eW2, eb2,
                                    (float*)d_out);
}

// Round 10
// 189.327 us; speedup vs baseline: 1.1652x; 1.1652x over previous
//
#include <hip/hip_runtime.h>
#include <hip/hip_bf16.h>

#define NB 2048
#define NNODES 64
#define HD 128
#define NEDGE 512
#define OSTRIDE 2017

using bf16x8 = __attribute__((ext_vector_type(8))) __bf16;
using f32x4  = __attribute__((ext_vector_type(4))) float;
using u32x4  = __attribute__((ext_vector_type(4))) unsigned int;

typedef __attribute__((address_space(1))) void gvoid;
typedef __attribute__((address_space(3))) void lvoid;

// XOR swizzle for [64][128] bf16 tiles (256-B rows).
__device__ __forceinline__ int swz(int row, int cb){ return (row<<8) + (cb ^ ((row&7)<<4)); }

__device__ __forceinline__ unsigned short bf16r(float x){
  unsigned u = __float_as_uint(x);
  return (unsigned short)((u + 0x7fffu + ((u>>16)&1u)) >> 16);  // RNE
}
__device__ __forceinline__ unsigned pack2(float a, float b){
  unsigned ua = __float_as_uint(a); ua = (ua + 0x7fffu + ((ua>>16)&1u)) >> 16;
  unsigned ub = __float_as_uint(b); ub = (ub + 0x7fffu + ((ub>>16)&1u)) & 0xffff0000u;
  return ua | ub;
}
__device__ __forceinline__ void unpack8(u32x4 u, float* f){
#pragma unroll
  for (int i=0;i<4;++i){
    unsigned w = u[i];
    f[2*i]   = __uint_as_float(w << 16);
    f[2*i+1] = __uint_as_float(w & 0xffff0000u);
  }
}
__device__ __forceinline__ bf16x8 asbf8(u32x4 u){ return __builtin_bit_cast(bf16x8, u); }
#define MFMA __builtin_amdgcn_mfma_f32_16x16x32_bf16

// ---- prep: bf16 [n][k-swz] slabs; Wc = W2@pW1 merged; plus eW1^T and triu table.
// ws (bf16 elems): w1 @0 (3x16384), wc @49152, pw2 @98304, emb @147456 (8192),
// bc f32[3][128] @155648 (768 slots), eW1T @156416 (16384), triuTab u32[2016] @172800.
__global__ void prep_wts(const float* __restrict__ g1, const float* __restrict__ g2,
                         const float* __restrict__ p1, const float* __restrict__ p2,
                         const float* __restrict__ b2, const float* __restrict__ pb1,
                         const float* __restrict__ emb, const float* __restrict__ eW1,
                         unsigned short* __restrict__ ws)
{
  int idx = blockIdx.x*256 + threadIdx.x;
  if (idx < 49152){            // W1^T swizzled
    int l = idx/16384, r = idx%16384, n = r>>7, m = r&127;
    int k = (((m>>3) ^ (n&7))<<3) | (m&7);
    ws[idx] = bf16r(g1[l*16384 + k*128 + n]);
  } else if (idx < 98304){     // Wc^T swizzled, Wc = W2 @ pW1 (f32 accumulate)
    int q = idx - 49152;
    int l = q/16384, r = q%16384, n = r>>7, m = r&127;
    int k = (((m>>3) ^ (n&7))<<3) | (m&7);
    const float* W2 = g2 + l*16384;
    const float* P1 = p1 + l*16384;
    float s = 0.f;
    for (int mm=0; mm<128; ++mm) s = fmaf(W2[k*128+mm], P1[mm*128+n], s);
    ws[idx] = bf16r(s);
  } else if (idx < 147456){    // pW2^T swizzled
    int q = idx - 98304;
    int l = q/16384, r = q%16384, n = r>>7, m = r&127;
    int k = (((m>>3) ^ (n&7))<<3) | (m&7);
    ws[idx] = bf16r(p2[l*16384 + k*128 + n]);
  } else if (idx < 155648){    // emb bf16
    ws[idx] = bf16r(emb[idx - 147456]);
  } else if (idx < 156032){    // bc[l][n] = b2[l]@pW1[l][:,n] + pb1[l][n]  (f32)
    int q = idx - 155648, l = q/128, n = q%128;
    const float* P1 = p1 + l*16384;
    const float* B2 = b2 + l*128;
    float s = pb1[l*128 + n];
    for (int mm=0; mm<128; ++mm) s = fmaf(B2[mm], P1[mm*128+n], s);
    ((float*)(ws + 155648))[q] = s;
  } else if (idx >= 156416 && idx < 172800){   // eW1^T bf16 [n][k]
    int q = idx - 156416, n = q>>7, k = q&127;
    ws[idx] = bf16r(eW1[k*128 + n]);
  } else if (idx >= 172800 && idx < 174816){   // triu (i,j) table
    int p = idx - 172800;
    float fi = (127.0f - sqrtf((float)(16129 - 8*p))) * 0.5f;
    int i = (int)fi;
    if (i > 62) i = 62;
    if (i < 0)  i = 0;
    while ((i+1)*(127-(i+1))/2 <= p) ++i;
    while (i*(127-i)/2 > p) --i;
    int j = i + 1 + (p - i*(127-i)/2);
    ((unsigned*)(ws + 172800))[p] = ((unsigned)i << 16) | (unsigned)j;
  }
}

// Async-stage one 16 KB half-slab global->LDS, linear. 8 waves x 2 issues x 1 KB.
__device__ __forceinline__ void stage(const unsigned short* g, unsigned char* lbuf, int t){
  const int l = t & 63, w = t >> 6;
  const unsigned char* gb = (const unsigned char*)g;
#pragma unroll
  for (int i=0;i<2;++i){
    int base = ((i*8 + w) << 10);
    __builtin_amdgcn_global_load_lds((gvoid*)(gb + base + l*16), (lvoid*)(lbuf + base), 16, 0, 0);
  }
}

// Wave w's 4 B-frags for its 16-col tile. Waves 0-3 <- bufA (slab rows 0-63),
// waves 4-7 <- bufB (rows 64-127).
__device__ __forceinline__ void ldw(const unsigned char* bufA, const unsigned char* bufB,
                                    int t, u32x4* wf){
  const int l = t & 63, w = t >> 6, lr = l & 15, lk = l >> 4;
  const unsigned char* buf = (w < 4) ? bufA : bufB;
  int n = (w & 3)*16 + lr;
  int rb = n << 8, sw = (n & 7) << 4;
#pragma unroll
  for (int ks=0; ks<4; ++ks)
    wf[ks] = *(const u32x4*)(buf + rb + ((ks*64 + lk*16) ^ sw));
}

// y = x @ W (wave w -> output col-tile w), written TRANSPOSED into yT.
__device__ __forceinline__ void gemm_yT(const unsigned char* xs, const u32x4* wf,
                                        unsigned char* yT, int t)
{
  const int l = t & 63, w = t >> 6, lr = l & 15, lk = l >> 4;
  f32x4 acc[4] = {};
#pragma unroll
  for (int ks=0; ks<4; ++ks){
    int kByte = ks*64 + lk*16;
    bf16x8 bw = asbf8(wf[ks]);
#pragma unroll
    for (int rt=0; rt<4; ++rt){
      bf16x8 af = asbf8(*(const u32x4*)(xs + swz(rt*16 + lr, kByte)));
      acc[rt] = MFMA(af, bw, acc[rt], 0,0,0);
    }
  }
  int n = w*16 + lr;                          // output col = yT row
  int sw = (n & 7) << 4;
#pragma unroll
  for (int rt=0; rt<4; ++rt){
    unsigned w0 = pack2(acc[rt][0], acc[rt][1]);
    unsigned w1 = pack2(acc[rt][2], acc[rt][3]);
    int cb = (rt*32 + lk*8) ^ sw;
    *(unsigned long long*)(yT + (n<<7) + cb) = ((unsigned long long)w1 << 32) | w0;
  }
}

// In-place 64x128 = (64x128)@(128x128) + bias, optional relu. Internal barrier.
template<int RELU>
__device__ __forceinline__ void gemm_st(unsigned char* hb, const u32x4* wf,
                                        const float* __restrict__ bias, int t)
{
  const int l = t & 63, w = t >> 6, lr = l & 15, lk = l >> 4;
  f32x4 acc[4] = {};
#pragma unroll
  for (int ks=0; ks<4; ++ks){
    int kByte = ks*64 + lk*16;
    bf16x8 bw = asbf8(wf[ks]);
#pragma unroll
    for (int rt=0; rt<4; ++rt){
      bf16x8 af = asbf8(*(const u32x4*)(hb + swz(rt*16 + lr, kByte)));
      acc[rt] = MFMA(af, bw, acc[rt], 0,0,0);
    }
  }
  int c0 = w*16 + lr;
  float b0 = bias[c0];
  __syncthreads();   // all A-reads complete; also drains this phase's staging
  int cb0 = c0*2;
#pragma unroll
  for (int rt=0; rt<4; ++rt){
#pragma unroll
    for (int r=0; r<4; ++r){
      int row = rt*16 + lk*4 + r;
      float v0 = acc[rt][r] + b0;
      if (RELU) v0 = fmaxf(v0, 0.f);
      *(unsigned short*)(hb + swz(row, cb0)) = bf16r(v0);
    }
  }
}

// h = A' @ y + bias (A' in sA_; y as yT rows in sH_). In-place on sH_.
__device__ __forceinline__ void gemm_aggA(const unsigned char* sA_, unsigned char* sH_,
                                          const float* __restrict__ bias, int t)
{
  const int l = t & 63, w = t >> 6, lr = l & 15, lk = l >> 4;
  f32x4 acc[4] = {};
  int n = w*16 + lr;                          // feat col (= yT row)
  int nsw = (n & 7) << 4;
#pragma unroll
  for (int ks=0; ks<2; ++ks){
    int kB = ks*64 + lk*16;
    bf16x8 bfr = asbf8(*(const u32x4*)(sH_ + (n<<7) + (kB ^ nsw)));
#pragma unroll
    for (int rt=0; rt<4; ++rt){
      int m = rt*16 + lr;
      bf16x8 af = asbf8(*(const u32x4*)(sA_ + (m<<7) + (kB ^ ((m&7)<<4))));
      acc[rt] = MFMA(af, bfr, acc[rt], 0,0,0);
    }
  }
  float b0 = bias[n];
  __syncthreads();   // all yT reads complete before overwrite
  int cb0 = n*2;
#pragma unroll
  for (int rt=0; rt<4; ++rt){
#pragma unroll
    for (int r=0; r<4; ++r){
      int row = rt*16 + lk*4 + r;
      *(unsigned short*)(sH_ + swz(row, cb0)) = bf16r(acc[rt][r] + b0);
    }
  }
}

// LayerNorm rows of a [64][128] bf16 tile. 512 thr: row t>>3, eighth t&7.
template<int RELU, int RESID>
__device__ __forceinline__ void ln_rows(const unsigned char* inb, const unsigned char* resb,
                                        const float* __restrict__ g, const float* __restrict__ bb,
                                        unsigned char* outb, int t)
{
  int r = t >> 3, e = t & 7;
  int cb0 = e*32, c0 = e*16;
  float v[16];
#pragma unroll
  for (int i=0;i<2;++i){ u32x4 u = *(const u32x4*)(inb + swz(r, cb0 + i*16)); unpack8(u, v + i*8); }
  if constexpr (RESID){
#pragma unroll
    for (int i=0;i<2;++i){
      u32x4 u = *(const u32x4*)(resb + swz(r, cb0 + i*16));
      float x[8]; unpack8(u, x);
#pragma unroll
      for (int j=0;j<8;++j) v[i*8+j] += x[j];
    }
  }
  float s=0.f, s2=0.f;
#pragma unroll
  for (int i=0;i<16;++i){ s += v[i]; s2 += v[i]*v[i]; }
  s += __shfl_xor(s, 1); s2 += __shfl_xor(s2, 1);
  s += __shfl_xor(s, 2); s2 += __shfl_xor(s2, 2);
  s += __shfl_xor(s, 4); s2 += __shfl_xor(s2, 4);
  float mu  = s * (1.f/128.f);
  float var = s2 * (1.f/128.f) - mu*mu;
  float rs  = rsqrtf(var + 1e-5f);
#pragma unroll
  for (int i=0;i<4;++i){
    f32x4 gv = *(const f32x4*)(g + c0 + i*4);
    f32x4 bv = *(const f32x4*)(bb + c0 + i*4);
#pragma unroll
    for (int j=0;j<4;++j){
      float val = (v[i*4+j]-mu)*rs*gv[j] + bv[j];
      if (RELU) val = fmaxf(val, 0.f);
      v[i*4+j] = val;
    }
  }
#pragma unroll
  for (int i=0;i<2;++i){
    u32x4 u;
#pragma unroll
    for (int j=0;j<4;++j) u[j] = pack2(v[i*8+2*j], v[i*8+2*j+1]);
    *(u32x4*)(outb + swz(r, cb0 + i*16)) = u;
  }
}

__global__ __launch_bounds__(512, 4) void gnn_fused(
    const int* __restrict__ nf, const int* __restrict__ ei,
    const unsigned short* __restrict__ wsb,
    const float* __restrict__ gb1, const float* __restrict__ glng, const float* __restrict__ glnb,
    const float* __restrict__ pb2,
    const float* __restrict__ nmg, const float* __restrict__ nmb,
    const float* __restrict__ eb1,
    const float* __restrict__ elng, const float* __restrict__ elnb,
    const float* __restrict__ eW2, const float* __restrict__ eb2,
    float* __restrict__ out)
{
  __shared__ __align__(16) unsigned char sX[16384];   // x tile [64][128] bf16 swizzled
  __shared__ __align__(16) unsigned char sH[16384];   // counts / yT / h / dots f32[64][64]
  __shared__ __align__(16) unsigned char sA[8192];    // feats -> A' -> exit scratch
  __shared__ __align__(16) unsigned char wbA[16384];  // weight half-slab transit
  __shared__ __align__(16) unsigned char wbB[16384];

  const int b = blockIdx.x, t = threadIdx.x;
  const int l = t & 63, w = t >> 6, lr = l & 15, lk = l >> 4;

  const unsigned short* wg1 = wsb;
  const unsigned short* wwc = wsb + 49152;
  const unsigned short* wp2 = wsb + 98304;
  const unsigned short* wem = wsb + 147456;
  const float*          bcf = (const float*)(wsb + 155648);
  const unsigned short* eT  = wsb + 156416;
  const unsigned*       tab = (const unsigned*)(wsb + 172800);

  // ---- setup: feats into sA, zero counts in sH ----
  if (t < NNODES) ((int*)sA)[t] = nf[b*NNODES + t];
  {
    u32x4 z = {0,0,0,0};
#pragma unroll
    for (int i=0;i<2;++i) *(u32x4*)(sH + t*32 + i*16) = z;   // 16 KB zeroed
  }
  __syncthreads();

  // x0 = emb[feat] ; edge multiplicity counts via LDS atomics
  {
    int n = t >> 3, e = t & 7;
    int f = ((const int*)sA)[n];
    const unsigned char* er = (const unsigned char*)(wem + f*HD) + e*32;
#pragma unroll
    for (int i=0;i<2;++i){
      u32x4 u = *(const u32x4*)(er + i*16);
      *(u32x4*)(sX + swz(n, e*32 + i*16)) = u;
    }
  }
  {
    int* cnts = (int*)sH;
    int sg = (ei[b*NEDGE + t]            - b*NNODES) & 63;
    int dg = (ei[NB*NEDGE + b*NEDGE + t] - b*NNODES) & 63;
    atomicAdd(&cnts[dg*64 + sg], 1);
  }
  __syncthreads();

  // stage layer-0 W1 (overlaps A'-build) + A' = A+I bf16 [64][64] swizzled into sA
  stage(wg1,        wbA, t);
  stage(wg1 + 8192, wbB, t);
  {
    const int* cnts = (const int*)sH;
    int n = t >> 3, c0 = (t & 7) * 8;
    unsigned short o[8];
#pragma unroll
    for (int j=0;j<8;++j){
      int v = cnts[n*64 + c0 + j];
      if (c0 + j == n) v += 1;
      o[j] = bf16r((float)v);
    }
    u32x4 u0;
#pragma unroll
    for (int j=0;j<4;++j) u0[j] = (unsigned)o[2*j] | ((unsigned)o[2*j+1] << 16);
    *(u32x4*)(sA + (n<<7) + ((c0*2) ^ ((n&7)<<4))) = u0;
  }
  __syncthreads();   // drains wg1 staging

  u32x4 wf[4];
  ldw(wbA, wbB, t, wf);       // W1[0] -> regs
  __syncthreads();            // transit free

  for (int i=0; i<3; ++i){
    // P1: stage Wc; yT = (x@W1)^T -> sH
    stage(wwc + i*16384,        wbA, t);
    stage(wwc + i*16384 + 8192, wbB, t);
    gemm_yT(sX, wf, sH, t);
    __syncthreads();                                   // yT visible; Wc staged
    // P2: h = A'@y + b1 (in-place sH, internal bar); pull Wc frags
    gemm_aggA(sA, sH, gb1 + i*HD, t);
    ldw(wbA, wbB, t, wf);
    __syncthreads();                                   // transit free
    // P3: stage pW2; u = relu(LN(h)) in-place
    stage(wp2 + i*16384,        wbA, t);
    stage(wp2 + i*16384 + 8192, wbB, t);
    ln_rows<1,0>(sH, nullptr, glng + i*HD, glnb + i*HD, sH, t);
    __syncthreads();                                   // pW2 staged (drain)
    // P4: v = relu(u@Wc + bc) in-place (internal bar); pull pW2 frags
    gemm_st<1>(sH, wf, bcf + i*HD, t);
    ldw(wbA, wbB, t, wf);
    __syncthreads();                                   // transit free
    // P5: stage next W1; h = v@pW2 + pb2 in-place (internal bar drains); pull W1
    if (i < 2){
      stage(wg1 + (i+1)*16384,        wbA, t);
      stage(wg1 + (i+1)*16384 + 8192, wbB, t);
    }
    gemm_st<0>(sH, wf, pb2 + i*HD, t);
    if (i < 2) ldw(wbA, wbB, t, wf);
    __syncthreads();
    // P6: x = LN(h [+x]) -> sX
    if (i == 0) ln_rows<0,0>(sH, nullptr, nmg, nmb, sX, t);
    else        ln_rows<0,1>(sH, sX,      nmg, nmb, sX, t);
    __syncthreads();
  }

  // exit-head scratch in sA (f32): part[512] @0, meansv[128] @512, m1p[512] @640, m1[128] @1152
  float* part   = (float*)sA;
  float* meansv = (float*)sA + 512;
  float* m1p    = (float*)sA + 640;
  float* m1     = (float*)sA + 1152;

  // ---- T1: dots MFMA (sX -> sH)  ||  column part-sums (sX -> sA) ----
  {
    int a = w & 3, ch = w >> 2;
    f32x4 dacc[2] = {};
#pragma unroll
    for (int ks=0; ks<4; ++ks){
      int kByte = ks*64 + lk*16;
      bf16x8 af = asbf8(*(const u32x4*)(sX + swz(a*16 + lr, kByte)));
#pragma unroll
      for (int cc=0; cc<2; ++cc){
        int ct = ch*2 + cc;
        bf16x8 bf = asbf8(*(const u32x4*)(sX + swz(ct*16 + lr, kByte)));
        dacc[cc] = MFMA(af, bf, dacc[cc], 0,0,0);
      }
    }
    float* dotsf = (float*)sH;
#pragma unroll
    for (int cc=0; cc<2; ++cc){
      int ct = ch*2 + cc;
#pragma unroll
      for (int r=0; r<4; ++r){
        int row = a*16 + lk*4 + r;
        int col = (ct*16 + lr) ^ (((row>>2)&1)<<4);
        dotsf[row*64 + col] = dacc[cc][r] * 0.08838834764831843f;
      }
    }
  }
  {
    int c = t & 127, q = t >> 7;
    float s = 0.f;
#pragma unroll
    for (int r2=0; r2<16; ++r2){
      unsigned short u = *(const unsigned short*)(sX + swz(q*16 + r2, 2*c));
      s += __uint_as_float(((unsigned)u) << 16);
    }
    part[q*128 + c] = s;
  }
  __syncthreads();

  // ---- T2: meansv + triu table-extraction ----
  if (t < 128) meansv[t] = (part[t] + part[128+t] + part[256+t] + part[384+t]) * (1.f/64.f);
  {
    const float* dotsf = (const float*)sH;
#pragma unroll
    for (int p = t; p < 2016; p += 512){
      unsigned ij = tab[p];
      int i = (int)(ij >> 16), j = (int)(ij & 0xffffu);
      int jc = j ^ (((i>>2)&1)<<4);
      out[(size_t)b*OSTRIDE + p] = dotsf[i*64 + jc];
    }
  }
  __syncthreads();

  // ---- T3: m1 = means @ eW1 + eb1, 4 lanes per output col (k-split quarters) ----
  {
    int c = t & 127, q = t >> 7;
    const unsigned short* er = eT + c*128 + q*32;
    float s = 0.f;
#pragma unroll
    for (int kk=0; kk<4; ++kk){
      u32x4 u = *(const u32x4*)(er + kk*8);
      float f[8]; unpack8(u, f);
#pragma unroll
      for (int j=0;j<8;++j) s += meansv[q*32 + kk*8 + j] * f[j];
    }
    m1p[q*128 + c] = s;
  }
  __syncthreads();
  if (t < 128) m1[t] = m1p[t] + m1p[128+t] + m1p[256+t] + m1p[384+t] + eb1[t];
  __syncthreads();

  // ---- T4: exit LN + final dot (wave 0) ----
  if (t < 64){
    float v0 = m1[t], v1 = m1[t+64];
    float s = v0 + v1, s2 = v0*v0 + v1*v1;
#pragma unroll
    for (int d=1; d<64; d<<=1){ s += __shfl_xor(s, d); s2 += __shfl_xor(s2, d); }
    float mu  = s * (1.f/128.f);
    float var = s2 * (1.f/128.f) - mu*mu;
    float rs  = rsqrtf(var + 1e-5f);
    float e0 = fmaxf((v0-mu)*rs*elng[t]    + elnb[t],    0.f);
    float e1 = fmaxf((v1-mu)*rs*elng[t+64] + elnb[t+64], 0.f);
    float pd = e0*eW2[t] + e1*eW2[t+64];
#pragma unroll
    for (int d=1; d<64; d<<=1) pd += __shfl_xor(pd, d);
    if (t == 0) out[(size_t)b*OSTRIDE + 2016] = pd + eb2[0];
  }
}

extern "C" void kernel_launch(void* const* d_in, const int* in_sizes, int n_in,
                              void* d_out, int out_size, void* d_ws, size_t ws_size,
                              hipStream_t stream)
{
  const int*   nf   = (const int*)d_in[0];
  const int*   ei   = (const int*)d_in[1];
  // d_in[2] = ptr (uniform 64-node graphs, unused)
  const float* emb  = (const float*)d_in[3];
  const float* gW1  = (const float*)d_in[4];
  const float* gb1  = (const float*)d_in[5];
  const float* glng = (const float*)d_in[6];
  const float* glnb = (const float*)d_in[7];
  const float* gW2  = (const float*)d_in[8];
  const float* gb2  = (const float*)d_in[9];
  const float* pW1  = (const float*)d_in[10];
  const float* pb1  = (const float*)d_in[11];
  const float* pW2  = (const float*)d_in[12];
  const float* pb2  = (const float*)d_in[13];
  const float* nmg  = (const float*)d_in[14];
  const float* nmb  = (const float*)d_in[15];
  const float* eW1  = (const float*)d_in[16];
  const float* eb1  = (const float*)d_in[17];
  const float* elng = (const float*)d_in[18];
  const float* elnb = (const float*)d_in[19];
  const float* eW2  = (const float*)d_in[20];
  const float* eb2  = (const float*)d_in[21];
  (void)in_sizes; (void)n_in; (void)out_size;

  if (ws_size < 176832u * sizeof(unsigned short)) return;
  unsigned short* wsb = (unsigned short*)d_ws;

  prep_wts<<<683, 256, 0, stream>>>(gW1, gW2, pW1, pW2, gb2, pb1, emb, eW1, wsb);
  gnn_fused<<<NB, 512, 0, stream>>>(nf, ei, wsb, gb1, glng, glnb, pb2,
                                    nmg, nmb, eb1, elng, elnb, eW2, eb2,
                                    (float*)d_out);
}

// Round 11
// 185.186 us; speedup vs baseline: 1.1912x; 1.0224x over previous
//
#include <hip/hip_runtime.h>
#include <hip/hip_bf16.h>

#define NB 2048
#define NNODES 64
#define HD 128
#define NEDGE 512
#define OSTRIDE 2017

using bf16x8 = __attribute__((ext_vector_type(8))) __bf16;
using f32x4  = __attribute__((ext_vector_type(4))) float;
using u32x4  = __attribute__((ext_vector_type(4))) unsigned int;

typedef __attribute__((address_space(1))) void gvoid;
typedef __attribute__((address_space(3))) void lvoid;

// XOR swizzle for [64][128] bf16 tiles (256-B rows).
__device__ __forceinline__ int swz(int row, int cb){ return (row<<8) + (cb ^ ((row&7)<<4)); }

__device__ __forceinline__ unsigned short bf16r(float x){
  unsigned u = __float_as_uint(x);
  return (unsigned short)((u + 0x7fffu + ((u>>16)&1u)) >> 16);  // RNE
}
__device__ __forceinline__ unsigned pack2(float a, float b){
  unsigned ua = __float_as_uint(a); ua = (ua + 0x7fffu + ((ua>>16)&1u)) >> 16;
  unsigned ub = __float_as_uint(b); ub = (ub + 0x7fffu + ((ub>>16)&1u)) & 0xffff0000u;
  return ua | ub;
}
__device__ __forceinline__ void unpack8(u32x4 u, float* f){
#pragma unroll
  for (int i=0;i<4;++i){
    unsigned w = u[i];
    f[2*i]   = __uint_as_float(w << 16);
    f[2*i+1] = __uint_as_float(w & 0xffff0000u);
  }
}
__device__ __forceinline__ bf16x8 asbf8(u32x4 u){ return __builtin_bit_cast(bf16x8, u); }
#define MFMA __builtin_amdgcn_mfma_f32_16x16x32_bf16

// ---- prep: bf16 [n][k-swz] slabs; Wc = W2@pW1 merged; plus eW1^T and triu table.
// ws (bf16 elems): w1 @0 (3x16384), wc @49152, pw2 @98304, emb @147456 (8192),
// bc f32[3][128] @155648 (768 slots), eW1T @156416 (16384), triuTab u32[2016] @172800.
__global__ void prep_wts(const float* __restrict__ g1, const float* __restrict__ g2,
                         const float* __restrict__ p1, const float* __restrict__ p2,
                         const float* __restrict__ b2, const float* __restrict__ pb1,
                         const float* __restrict__ emb, const float* __restrict__ eW1,
                         unsigned short* __restrict__ ws)
{
  int idx = blockIdx.x*256 + threadIdx.x;
  if (idx < 49152){            // W1^T swizzled
    int l = idx/16384, r = idx%16384, n = r>>7, m = r&127;
    int k = (((m>>3) ^ (n&7))<<3) | (m&7);
    ws[idx] = bf16r(g1[l*16384 + k*128 + n]);
  } else if (idx < 98304){     // Wc^T swizzled, Wc = W2 @ pW1 (f32 accumulate)
    int q = idx - 49152;
    int l = q/16384, r = q%16384, n = r>>7, m = r&127;
    int k = (((m>>3) ^ (n&7))<<3) | (m&7);
    const float* W2 = g2 + l*16384;
    const float* P1 = p1 + l*16384;
    float s = 0.f;
    for (int mm=0; mm<128; ++mm) s = fmaf(W2[k*128+mm], P1[mm*128+n], s);
    ws[idx] = bf16r(s);
  } else if (idx < 147456){    // pW2^T swizzled
    int q = idx - 98304;
    int l = q/16384, r = q%16384, n = r>>7, m = r&127;
    int k = (((m>>3) ^ (n&7))<<3) | (m&7);
    ws[idx] = bf16r(p2[l*16384 + k*128 + n]);
  } else if (idx < 155648){    // emb bf16
    ws[idx] = bf16r(emb[idx - 147456]);
  } else if (idx < 156032){    // bc[l][n] = b2[l]@pW1[l][:,n] + pb1[l][n]  (f32)
    int q = idx - 155648, l = q/128, n = q%128;
    const float* P1 = p1 + l*16384;
    const float* B2 = b2 + l*128;
    float s = pb1[l*128 + n];
    for (int mm=0; mm<128; ++mm) s = fmaf(B2[mm], P1[mm*128+n], s);
    ((float*)(ws + 155648))[q] = s;
  } else if (idx >= 156416 && idx < 172800){   // eW1^T bf16 [n][k]
    int q = idx - 156416, n = q>>7, k = q&127;
    ws[idx] = bf16r(eW1[k*128 + n]);
  } else if (idx >= 172800 && idx < 174816){   // triu (i,j) table
    int p = idx - 172800;
    float fi = (127.0f - sqrtf((float)(16129 - 8*p))) * 0.5f;
    int i = (int)fi;
    if (i > 62) i = 62;
    if (i < 0)  i = 0;
    while ((i+1)*(127-(i+1))/2 <= p) ++i;
    while (i*(127-i)/2 > p) --i;
    int j = i + 1 + (p - i*(127-i)/2);
    ((unsigned*)(ws + 172800))[p] = ((unsigned)i << 16) | (unsigned)j;
  }
}

// Async-stage one 16 KB half-slab global->LDS, linear. 8 waves x 2 issues x 1 KB.
__device__ __forceinline__ void stage(const unsigned short* g, unsigned char* lbuf, int t){
  const int l = t & 63, w = t >> 6;
  const unsigned char* gb = (const unsigned char*)g;
#pragma unroll
  for (int i=0;i<2;++i){
    int base = ((i*8 + w) << 10);
    __builtin_amdgcn_global_load_lds((gvoid*)(gb + base + l*16), (lvoid*)(lbuf + base), 16, 0, 0);
  }
}

// Wave w's 4 B-frags for its 16-col tile. Waves 0-3 <- bufA (slab rows 0-63),
// waves 4-7 <- bufB (rows 64-127).
__device__ __forceinline__ void ldw(const unsigned char* bufA, const unsigned char* bufB,
                                    int t, u32x4* wf){
  const int l = t & 63, w = t >> 6, lr = l & 15, lk = l >> 4;
  const unsigned char* buf = (w < 4) ? bufA : bufB;
  int n = (w & 3)*16 + lr;
  int rb = n << 8, sw = (n & 7) << 4;
#pragma unroll
  for (int ks=0; ks<4; ++ks)
    wf[ks] = *(const u32x4*)(buf + rb + ((ks*64 + lk*16) ^ sw));
}

// y = x @ W (wave w -> output col-tile w), written TRANSPOSED into yT.
__device__ __forceinline__ void gemm_yT(const unsigned char* xs, const u32x4* wf,
                                        unsigned char* yT, int t)
{
  const int l = t & 63, w = t >> 6, lr = l & 15, lk = l >> 4;
  f32x4 acc[4] = {};
#pragma unroll
  for (int ks=0; ks<4; ++ks){
    int kByte = ks*64 + lk*16;
    bf16x8 bw = asbf8(wf[ks]);
#pragma unroll
    for (int rt=0; rt<4; ++rt){
      bf16x8 af = asbf8(*(const u32x4*)(xs + swz(rt*16 + lr, kByte)));
      acc[rt] = MFMA(af, bw, acc[rt], 0,0,0);
    }
  }
  int n = w*16 + lr;                          // output col = yT row
  int sw = (n & 7) << 4;
#pragma unroll
  for (int rt=0; rt<4; ++rt){
    unsigned w0 = pack2(acc[rt][0], acc[rt][1]);
    unsigned w1 = pack2(acc[rt][2], acc[rt][3]);
    int cb = (rt*32 + lk*8) ^ sw;
    *(unsigned long long*)(yT + (n<<7) + cb) = ((unsigned long long)w1 << 32) | w0;
  }
}

// In-place 64x128 = (64x128)@(128x128) + bias, optional relu. Internal barrier.
template<int RELU>
__device__ __forceinline__ void gemm_st(unsigned char* hb, const u32x4* wf,
                                        const float* __restrict__ bias, int t)
{
  const int l = t & 63, w = t >> 6, lr = l & 15, lk = l >> 4;
  f32x4 acc[4] = {};
#pragma unroll
  for (int ks=0; ks<4; ++ks){
    int kByte = ks*64 + lk*16;
    bf16x8 bw = asbf8(wf[ks]);
#pragma unroll
    for (int rt=0; rt<4; ++rt){
      bf16x8 af = asbf8(*(const u32x4*)(hb + swz(rt*16 + lr, kByte)));
      acc[rt] = MFMA(af, bw, acc[rt], 0,0,0);
    }
  }
  int c0 = w*16 + lr;
  float b0 = bias[c0];
  __syncthreads();   // all A-reads complete; also drains this phase's staging
  int cb0 = c0*2;
#pragma unroll
  for (int rt=0; rt<4; ++rt){
#pragma unroll
    for (int r=0; r<4; ++r){
      int row = rt*16 + lk*4 + r;
      float v0 = acc[rt][r] + b0;
      if (RELU) v0 = fmaxf(v0, 0.f);
      *(unsigned short*)(hb + swz(row, cb0)) = bf16r(v0);
    }
  }
}

// h = A' @ y + bias (A' in sA_; y as yT rows in sH_). In-place on sH_.
__device__ __forceinline__ void gemm_aggA(const unsigned char* sA_, unsigned char* sH_,
                                          const float* __restrict__ bias, int t)
{
  const int l = t & 63, w = t >> 6, lr = l & 15, lk = l >> 4;
  f32x4 acc[4] = {};
  int n = w*16 + lr;                          // feat col (= yT row)
  int nsw = (n & 7) << 4;
#pragma unroll
  for (int ks=0; ks<2; ++ks){
    int kB = ks*64 + lk*16;
    bf16x8 bfr = asbf8(*(const u32x4*)(sH_ + (n<<7) + (kB ^ nsw)));
#pragma unroll
    for (int rt=0; rt<4; ++rt){
      int m = rt*16 + lr;
      bf16x8 af = asbf8(*(const u32x4*)(sA_ + (m<<7) + (kB ^ ((m&7)<<4))));
      acc[rt] = MFMA(af, bfr, acc[rt], 0,0,0);
    }
  }
  float b0 = bias[n];
  __syncthreads();   // all yT reads complete before overwrite
  int cb0 = n*2;
#pragma unroll
  for (int rt=0; rt<4; ++rt){
#pragma unroll
    for (int r=0; r<4; ++r){
      int row = rt*16 + lk*4 + r;
      *(unsigned short*)(sH_ + swz(row, cb0)) = bf16r(acc[rt][r] + b0);
    }
  }
}

// LayerNorm rows of a [64][128] bf16 tile. 512 thr: row t>>3, eighth t&7.
template<int RELU, int RESID>
__device__ __forceinline__ void ln_rows(const unsigned char* inb, const unsigned char* resb,
                                        const float* __restrict__ g, const float* __restrict__ bb,
                                        unsigned char* outb, int t)
{
  int r = t >> 3, e = t & 7;
  int cb0 = e*32, c0 = e*16;
  float v[16];
#pragma unroll
  for (int i=0;i<2;++i){ u32x4 u = *(const u32x4*)(inb + swz(r, cb0 + i*16)); unpack8(u, v + i*8); }
  if constexpr (RESID){
#pragma unroll
    for (int i=0;i<2;++i){
      u32x4 u = *(const u32x4*)(resb + swz(r, cb0 + i*16));
      float x[8]; unpack8(u, x);
#pragma unroll
      for (int j=0;j<8;++j) v[i*8+j] += x[j];
    }
  }
  float s=0.f, s2=0.f;
#pragma unroll
  for (int i=0;i<16;++i){ s += v[i]; s2 += v[i]*v[i]; }
  s += __shfl_xor(s, 1); s2 += __shfl_xor(s2, 1);
  s += __shfl_xor(s, 2); s2 += __shfl_xor(s2, 2);
  s += __shfl_xor(s, 4); s2 += __shfl_xor(s2, 4);
  float mu  = s * (1.f/128.f);
  float var = s2 * (1.f/128.f) - mu*mu;
  float rs  = rsqrtf(var + 1e-5f);
#pragma unroll
  for (int i=0;i<4;++i){
    f32x4 gv = *(const f32x4*)(g + c0 + i*4);
    f32x4 bv = *(const f32x4*)(bb + c0 + i*4);
#pragma unroll
    for (int j=0;j<4;++j){
      float val = (v[i*4+j]-mu)*rs*gv[j] + bv[j];
      if (RELU) val = fmaxf(val, 0.f);
      v[i*4+j] = val;
    }
  }
#pragma unroll
  for (int i=0;i<2;++i){
    u32x4 u;
#pragma unroll
    for (int j=0;j<4;++j) u[j] = pack2(v[i*8+2*j], v[i*8+2*j+1]);
    *(u32x4*)(outb + swz(r, cb0 + i*16)) = u;
  }
}

__global__ __launch_bounds__(512, 2) void gnn_fused(
    const int* __restrict__ nf, const int* __restrict__ ei,
    const unsigned short* __restrict__ wsb,
    const float* __restrict__ gb1, const float* __restrict__ glng, const float* __restrict__ glnb,
    const float* __restrict__ pb2,
    const float* __restrict__ nmg, const float* __restrict__ nmb,
    const float* __restrict__ eb1,
    const float* __restrict__ elng, const float* __restrict__ elnb,
    const float* __restrict__ eW2, const float* __restrict__ eb2,
    float* __restrict__ out)
{
  __shared__ __align__(16) unsigned char sX[16384];   // x tile [64][128] bf16 swizzled
  __shared__ __align__(16) unsigned char sH[16384];   // counts / yT / h / dots f32[64][64]
  __shared__ __align__(16) unsigned char sA[8192];    // feats -> A' -> exit scratch
  __shared__ __align__(16) unsigned char wbA[16384];  // weight half-slab transit
  __shared__ __align__(16) unsigned char wbB[16384];

  const int b = blockIdx.x, t = threadIdx.x;
  const int l = t & 63, w = t >> 6, lr = l & 15, lk = l >> 4;

  const unsigned short* wg1 = wsb;
  const unsigned short* wwc = wsb + 49152;
  const unsigned short* wp2 = wsb + 98304;
  const unsigned short* wem = wsb + 147456;
  const float*          bcf = (const float*)(wsb + 155648);
  const unsigned short* eT  = wsb + 156416;
  const unsigned*       tab = (const unsigned*)(wsb + 172800);

  // ---- setup: feats into sA, zero counts in sH ----
  if (t < NNODES) ((int*)sA)[t] = nf[b*NNODES + t];
  {
    u32x4 z = {0,0,0,0};
#pragma unroll
    for (int i=0;i<2;++i) *(u32x4*)(sH + t*32 + i*16) = z;   // 16 KB zeroed
  }
  __syncthreads();

  // x0 = emb[feat] ; edge multiplicity counts via LDS atomics
  {
    int n = t >> 3, e = t & 7;
    int f = ((const int*)sA)[n];
    const unsigned char* er = (const unsigned char*)(wem + f*HD) + e*32;
#pragma unroll
    for (int i=0;i<2;++i){
      u32x4 u = *(const u32x4*)(er + i*16);
      *(u32x4*)(sX + swz(n, e*32 + i*16)) = u;
    }
  }
  {
    int* cnts = (int*)sH;
    int sg = (ei[b*NEDGE + t]            - b*NNODES) & 63;
    int dg = (ei[NB*NEDGE + b*NEDGE + t] - b*NNODES) & 63;
    atomicAdd(&cnts[dg*64 + sg], 1);
  }
  __syncthreads();

  // stage layer-0 W1 (overlaps A'-build) + A' = A+I bf16 [64][64] swizzled into sA
  stage(wg1,        wbA, t);
  stage(wg1 + 8192, wbB, t);
  {
    const int* cnts = (const int*)sH;
    int n = t >> 3, c0 = (t & 7) * 8;
    unsigned short o[8];
#pragma unroll
    for (int j=0;j<8;++j){
      int v = cnts[n*64 + c0 + j];
      if (c0 + j == n) v += 1;
      o[j] = bf16r((float)v);
    }
    u32x4 u0;
#pragma unroll
    for (int j=0;j<4;++j) u0[j] = (unsigned)o[2*j] | ((unsigned)o[2*j+1] << 16);
    *(u32x4*)(sA + (n<<7) + ((c0*2) ^ ((n&7)<<4))) = u0;
  }
  __syncthreads();   // drains wg1 staging

  u32x4 wf[4];
  ldw(wbA, wbB, t, wf);       // W1[0] -> regs
  __syncthreads();            // transit free

  for (int i=0; i<3; ++i){
    // P1: stage Wc; yT = (x@W1)^T -> sH
    stage(wwc + i*16384,        wbA, t);
    stage(wwc + i*16384 + 8192, wbB, t);
    gemm_yT(sX, wf, sH, t);
    __syncthreads();                                   // yT visible; Wc staged
    // P2: h = A'@y + b1 (in-place sH, internal bar); pull Wc frags
    gemm_aggA(sA, sH, gb1 + i*HD, t);
    ldw(wbA, wbB, t, wf);
    __syncthreads();                                   // transit free
    // P3: stage pW2; u = relu(LN(h)) in-place
    stage(wp2 + i*16384,        wbA, t);
    stage(wp2 + i*16384 + 8192, wbB, t);
    ln_rows<1,0>(sH, nullptr, glng + i*HD, glnb + i*HD, sH, t);
    __syncthreads();                                   // pW2 staged (drain)
    // P4: v = relu(u@Wc + bc) in-place (internal bar); pull pW2 frags
    gemm_st<1>(sH, wf, bcf + i*HD, t);
    ldw(wbA, wbB, t, wf);
    __syncthreads();                                   // transit free
    // P5: stage next W1; h = v@pW2 + pb2 in-place (internal bar drains); pull W1
    if (i < 2){
      stage(wg1 + (i+1)*16384,        wbA, t);
      stage(wg1 + (i+1)*16384 + 8192, wbB, t);
    }
    gemm_st<0>(sH, wf, pb2 + i*HD, t);
    if (i < 2) ldw(wbA, wbB, t, wf);
    __syncthreads();
    // P6: x = LN(h [+x]) -> sX
    if (i == 0) ln_rows<0,0>(sH, nullptr, nmg, nmb, sX, t);
    else        ln_rows<0,1>(sH, sX,      nmg, nmb, sX, t);
    __syncthreads();
  }

  // exit-head scratch in sA (f32): part[512] @0, meansv[128] @512, m1p[512] @640, m1[128] @1152
  float* part   = (float*)sA;
  float* meansv = (float*)sA + 512;
  float* m1p    = (float*)sA + 640;
  float* m1     = (float*)sA + 1152;

  // ---- T1: dots MFMA (sX -> sH)  ||  column part-sums (sX -> sA) ----
  {
    int a = w & 3, ch = w >> 2;
    f32x4 dacc[2] = {};
#pragma unroll
    for (int ks=0; ks<4; ++ks){
      int kByte = ks*64 + lk*16;
      bf16x8 af = asbf8(*(const u32x4*)(sX + swz(a*16 + lr, kByte)));
#pragma unroll
      for (int cc=0; cc<2; ++cc){
        int ct = ch*2 + cc;
        bf16x8 bf = asbf8(*(const u32x4*)(sX + swz(ct*16 + lr, kByte)));
        dacc[cc] = MFMA(af, bf, dacc[cc], 0,0,0);
      }
    }
    float* dotsf = (float*)sH;
#pragma unroll
    for (int cc=0; cc<2; ++cc){
      int ct = ch*2 + cc;
#pragma unroll
      for (int r=0; r<4; ++r){
        int row = a*16 + lk*4 + r;
        int col = (ct*16 + lr) ^ (((row>>2)&1)<<4);
        dotsf[row*64 + col] = dacc[cc][r] * 0.08838834764831843f;
      }
    }
  }
  {
    int c = t & 127, q = t >> 7;
    float s = 0.f;
#pragma unroll
    for (int r2=0; r2<16; ++r2){
      unsigned short u = *(const unsigned short*)(sX + swz(q*16 + r2, 2*c));
      s += __uint_as_float(((unsigned)u) << 16);
    }
    part[q*128 + c] = s;
  }
  __syncthreads();

  // ---- T2: meansv + triu table-extraction ----
  if (t < 128) meansv[t] = (part[t] + part[128+t] + part[256+t] + part[384+t]) * (1.f/64.f);
  {
    const float* dotsf = (const float*)sH;
#pragma unroll
    for (int p = t; p < 2016; p += 512){
      unsigned ij = tab[p];
      int i = (int)(ij >> 16), j = (int)(ij & 0xffffu);
      int jc = j ^ (((i>>2)&1)<<4);
      out[(size_t)b*OSTRIDE + p] = dotsf[i*64 + jc];
    }
  }
  __syncthreads();

  // ---- T3: m1 = means @ eW1 + eb1, 4 lanes per output col (k-split quarters) ----
  {
    int c = t & 127, q = t >> 7;
    const unsigned short* er = eT + c*128 + q*32;
    float s = 0.f;
#pragma unroll
    for (int kk=0; kk<4; ++kk){
      u32x4 u = *(const u32x4*)(er + kk*8);
      float f[8]; unpack8(u, f);
#pragma unroll
      for (int j=0;j<8;++j) s += meansv[q*32 + kk*8 + j] * f[j];
    }
    m1p[q*128 + c] = s;
  }
  __syncthreads();
  if (t < 128) m1[t] = m1p[t] + m1p[128+t] + m1p[256+t] + m1p[384+t] + eb1[t];
  __syncthreads();

  // ---- T4: exit LN + final dot (wave 0) ----
  if (t < 64){
    float v0 = m1[t], v1 = m1[t+64];
    float s = v0 + v1, s2 = v0*v0 + v1*v1;
#pragma unroll
    for (int d=1; d<64; d<<=1){ s += __shfl_xor(s, d); s2 += __shfl_xor(s2, d); }
    float mu  = s * (1.f/128.f);
    float var = s2 * (1.f/128.f) - mu*mu;
    float rs  = rsqrtf(var + 1e-5f);
    float e0 = fmaxf((v0-mu)*rs*elng[t]    + elnb[t],    0.f);
    float e1 = fmaxf((v1-mu)*rs*elng[t+64] + elnb[t+64], 0.f);
    float pd = e0*eW2[t] + e1*eW2[t+64];
#pragma unroll
    for (int d=1; d<64; d<<=1) pd += __shfl_xor(pd, d);
    if (t == 0) out[(size_t)b*OSTRIDE + 2016] = pd + eb2[0];
  }
}

extern "C" void kernel_launch(void* const* d_in, const int* in_sizes, int n_in,
                              void* d_out, int out_size, void* d_ws, size_t ws_size,
                              hipStream_t stream)
{
  const int*   nf   = (const int*)d_in[0];
  const int*   ei   = (const int*)d_in[1];
  // d_in[2] = ptr (uniform 64-node graphs, unused)
  const float* emb  = (const float*)d_in[3];
  const float* gW1  = (const float*)d_in[4];
  const float* gb1  = (const float*)d_in[5];
  const float* glng = (const float*)d_in[6];
  const float* glnb = (const float*)d_in[7];
  const float* gW2  = (const float*)d_in[8];
  const float* gb2  = (const float*)d_in[9];
  const float* pW1  = (const float*)d_in[10];
  const float* pb1  = (const float*)d_in[11];
  const float* pW2  = (const float*)d_in[12];
  const float* pb2  = (const float*)d_in[13];
  const float* nmg  = (const float*)d_in[14];
  const float* nmb  = (const float*)d_in[15];
  const float* eW1  = (const float*)d_in[16];
  const float* eb1  = (const float*)d_in[17];
  const float* elng = (const float*)d_in[18];
  const float* elnb = (const float*)d_in[19];
  const float* eW2  = (const float*)d_in[20];
  const float* eb2  = (const float*)d_in[21];
  (void)in_sizes; (void)n_in; (void)out_size;

  if (ws_size < 176832u * sizeof(unsigned short)) return;
  unsigned short* wsb = (unsigned short*)d_ws;

  prep_wts<<<683, 256, 0, stream>>>(gW1, gW2, pW1, pW2, gb2, pb1, emb, eW1, wsb);
  gnn_fused<<<NB, 512, 0, stream>>>(nf, ei, wsb, gb1, glng, glnb, pb2,
                                    nmg, nmb, eb1, elng, elnb, eW2, eb2,
                                    (float*)d_out);
}